// Round 9
// baseline (173.240 us; speedup 1.0000x reference)
//
#include <hip/hip_runtime.h>
#include <hip/hip_bf16.h>

typedef __hip_bfloat16 bf16;
typedef unsigned short u16;
typedef __attribute__((ext_vector_type(8))) short bf16x8;
typedef __attribute__((ext_vector_type(4))) float f32x4;
typedef __attribute__((ext_vector_type(16))) float f32x16;

static constexpr int Bn = 8;
static constexpr int C = 512;
static constexpr int S = 1024;
static constexpr int NH = 8;
static constexpr int HD = 64;
static constexpr int CPG = 16;
#define EPSV 1e-5f
#define QSCALE 0.18033688011112042f  /* 0.125 * log2(e): folds attn scale + exp->exp2 */

__device__ __forceinline__ u16 f2bf(float f) {
    bf16 h = __float2bfloat16(f);
    return *reinterpret_cast<u16*>(&h);
}
__device__ __forceinline__ unsigned pack_bf2(float a, float b) {
    __hip_bfloat162 h = __float22bfloat162_rn(make_float2(a, b));
    return *reinterpret_cast<unsigned*>(&h);
}

// async global->LDS, 16B per lane; LDS dest = wave-uniform base + lane*16
__device__ __forceinline__ void async_copy16(const void* g, void* l) {
    __builtin_amdgcn_global_load_lds(
        (const __attribute__((address_space(1))) void*)g,
        (__attribute__((address_space(3))) void*)l, 16, 0, 0);
}

// ---- prep: blocks 0-255 GroupNorm stats; blocks 256-1279 weight fp32->bf16 ----
__global__ __launch_bounds__(256) void prep(const float* __restrict__ x,
                                            const float* __restrict__ wqkv,
                                            const float* __restrict__ wproj,
                                            float* __restrict__ stats,
                                            u16* __restrict__ wbf) {
    const int tid = threadIdx.x;
    if (blockIdx.x < 256) {
        const int bg = blockIdx.x;
        const size_t base = (size_t)bg * CPG * S;
        const int N = CPG * S;  // 16384
        float sum = 0.f, sq = 0.f;
        for (int i = tid * 4; i < N; i += 1024) {
            float4 v = *reinterpret_cast<const float4*>(&x[base + i]);
            sum += v.x + v.y + v.z + v.w;
            sq += v.x * v.x + v.y * v.y + v.z * v.z + v.w * v.w;
        }
#pragma unroll
        for (int off = 32; off > 0; off >>= 1) {
            sum += __shfl_down(sum, off, 64);
            sq  += __shfl_down(sq,  off, 64);
        }
        __shared__ float s0[4], s1[4];
        if ((tid & 63) == 0) { s0[tid >> 6] = sum; s1[tid >> 6] = sq; }
        __syncthreads();
        if (tid == 0) {
            float a  = s0[0] + s0[1] + s0[2] + s0[3];
            float b2 = s1[0] + s1[1] + s1[2] + s1[3];
            float mu = a / (float)N;
            float var = fmaxf(b2 / (float)N - mu * mu, 0.f);
            stats[bg] = mu;
            stats[256 + bg] = rsqrtf(var + EPSV);
        }
    } else {
        int idx = (blockIdx.x - 256) * 1024 + tid * 4;  // 2048*512 total
        float4 v;
        float sc = 1.f;
        if (idx < 1536 * 512) {
            v = *reinterpret_cast<const float4*>(&wqkv[idx]);
            if (idx < 512 * 512) sc = QSCALE;  // Q rows
        } else {
            v = *reinterpret_cast<const float4*>(&wproj[idx - 1536 * 512]);
        }
        u16 t[4] = {f2bf(v.x * sc), f2bf(v.y * sc), f2bf(v.z * sc), f2bf(v.w * sc)};
        *reinterpret_cast<uint2*>(&wbf[idx]) = *reinterpret_cast<uint2*>(t);
    }
}

// ------- GN apply + transpose: x[b][c][s] fp32 -> xnt[b][s][c] bf16 -------
__global__ __launch_bounds__(256) void gn_apply_t(const float* __restrict__ x,
                                                  const float* __restrict__ gamma,
                                                  const float* __restrict__ beta,
                                                  const float* __restrict__ stats,
                                                  u16* __restrict__ xnt) {
    const int b = blockIdx.z, c0 = blockIdx.y * 64, s0 = blockIdx.x * 64;
    const int tid = threadIdx.x;
    __shared__ u16 T[64 * 72];
    const float* xb = x + ((size_t)b * C + c0) * S;
#pragma unroll
    for (int i = 0; i < 4; ++i) {
        int ch = i * 256 + tid;
        int c = ch >> 4, seg = ch & 15;
        int cg = c0 + c;
        float mu = stats[b * 32 + (cg >> 4)];
        float rstd = stats[256 + b * 32 + (cg >> 4)];
        float ga = gamma[cg], be = beta[cg];
        float4 v = *reinterpret_cast<const float4*>(&xb[(size_t)c * S + s0 + seg * 4]);
        float vals[4] = {v.x, v.y, v.z, v.w};
#pragma unroll
        for (int j = 0; j < 4; ++j)
            T[(seg * 4 + j) * 72 + c] = f2bf((vals[j] - mu) * rstd * ga + be);
    }
    __syncthreads();
#pragma unroll
    for (int i = 0; i < 2; ++i) {
        int ch = i * 256 + tid;
        int r = ch >> 3, seg = ch & 7;
        uint4 val = *reinterpret_cast<const uint4*>(&T[r * 72 + seg * 8]);
        *reinterpret_cast<uint4*>(&xnt[(size_t)(b * S + s0 + r) * C + c0 + seg * 8]) = val;
    }
}

// ------- MFMA GEMM: BK=32, double-buffered LDS, one barrier per K-iter -------
// A from pre-converted bf16 weights Wb (DMA). Xt bf16 [b][s][512] k-contiguous.
// MODE 0 (qkv): o<1024 (q,k) -> qkvT[b][s][1024] transposed; o>=1024 (v) -> qkvV.
// MODE 1 (proj): fp32 output + residual.
template <int MODE>
__global__ __launch_bounds__(256) void mfma_gemm(const u16* __restrict__ Wb,
                                                 const u16* __restrict__ Xt,
                                                 const float* __restrict__ bias,
                                                 const float* __restrict__ resid,
                                                 u16* __restrict__ qkvT,
                                                 u16* __restrict__ qkvV,
                                                 float* __restrict__ Yf) {
    const int K = 512;
    const int b = blockIdx.z, o0 = blockIdx.y * 128, s0 = blockIdx.x * 128;
    const int tid = threadIdx.x;
    const int lane = tid & 63, w = tid >> 6;
    const int quad = lane >> 4, l15 = lane & 15;
    const int wr = w >> 1, wc = w & 1;
    __shared__ u16 As[2][128 * 32];  // 8 KB/buf: row r = 4 chunks, chunk c at c^(r&3)
    __shared__ u16 Bs[2][128 * 32];
    f32x4 acc[4][4] = {};
    const u16* Xb = Xt + (size_t)(b * S + s0) * K;
    const int rA = lane >> 2, cA = lane & 3;

    auto stage = [&](int bb, int k0) {
#pragma unroll
        for (int i = 0; i < 2; ++i) {
            int ci = w * 2 + i;
            int r = ci * 16 + rA;
            int cs = cA ^ (r & 3);
            async_copy16(&Wb[(size_t)(o0 + r) * K + k0 + cs * 8], &As[bb][ci * 512]);
            async_copy16(&Xb[(size_t)r * K + k0 + cs * 8], &Bs[bb][ci * 512]);
        }
    };
    stage(0, 0);
    __syncthreads();
    for (int t = 0; t < 16; ++t) {
        const int cur = t & 1;
        if (t < 15) stage(cur ^ 1, (t + 1) * 32);  // prefetch overlaps compute
        bf16x8 af[4], bfr[4];
#pragma unroll
        for (int mt = 0; mt < 4; ++mt) {
            int R = wr * 64 + mt * 16 + l15;
            af[mt] = *reinterpret_cast<const bf16x8*>(
                &As[cur][R * 32 + ((quad ^ (R & 3)) << 3)]);
        }
#pragma unroll
        for (int nt = 0; nt < 4; ++nt) {
            int R = wc * 64 + nt * 16 + l15;
            bfr[nt] = *reinterpret_cast<const bf16x8*>(
                &Bs[cur][R * 32 + ((quad ^ (R & 3)) << 3)]);
        }
#pragma unroll
        for (int mt = 0; mt < 4; ++mt)
#pragma unroll
            for (int nt = 0; nt < 4; ++nt)
                acc[mt][nt] = __builtin_amdgcn_mfma_f32_16x16x32_bf16(
                    af[mt], bfr[nt], acc[mt][nt], 0, 0, 0);
        __syncthreads();  // drains prefetch (a full compute phase in flight)
    }
    if (MODE == 1) {
#pragma unroll
        for (int mt = 0; mt < 4; ++mt) {
#pragma unroll
            for (int reg = 0; reg < 4; ++reg) {
                int o = o0 + wr * 64 + mt * 16 + quad * 4 + reg;
                float bz = bias[o];
#pragma unroll
                for (int nt = 0; nt < 4; ++nt) {
                    int s = s0 + wc * 64 + nt * 16 + l15;
                    size_t idx = (size_t)(b * C + o) * S + s;
                    Yf[idx] = acc[mt][nt][reg] + bz + resid[idx];
                }
            }
        }
    } else if (o0 < 1024) {
        // q,k -> [b][s][1024]; q bias gets QSCALE (matches pre-scaled Q weights)
        float bsc = (o0 < 512) ? QSCALE : 1.f;
#pragma unroll
        for (int mt = 0; mt < 4; ++mt) {
            int o_b = o0 + wr * 64 + mt * 16 + quad * 4;
            float bz[4];
#pragma unroll
            for (int reg = 0; reg < 4; ++reg) bz[reg] = bias[o_b + reg] * bsc;
#pragma unroll
            for (int nt = 0; nt < 4; ++nt) {
                int s = s0 + wc * 64 + nt * 16 + l15;
                uint2 pk;
                pk.x = pack_bf2(acc[mt][nt][0] + bz[0], acc[mt][nt][1] + bz[1]);
                pk.y = pack_bf2(acc[mt][nt][2] + bz[2], acc[mt][nt][3] + bz[3]);
                *reinterpret_cast<uint2*>(&qkvT[(size_t)(b * S + s) * 1024 + o_b]) = pk;
            }
        }
    } else {
        // v -> [b][v-channel][S]
#pragma unroll
        for (int mt = 0; mt < 4; ++mt) {
#pragma unroll
            for (int reg = 0; reg < 4; ++reg) {
                int o = o0 - 1024 + wr * 64 + mt * 16 + quad * 4 + reg;
                float bz = bias[o + 1024];
#pragma unroll
                for (int nt = 0; nt < 4; ++nt) {
                    int s = s0 + wc * 64 + nt * 16 + l15;
                    qkvV[(size_t)(b * 512 + o) * S + s] = f2bf(acc[mt][nt][reg] + bz);
                }
            }
        }
    }
}

// ---- MFMA flash attention v3: 32x32x16, Q in regs, P in regs (xor-32 swap) ----
// qkvT bf16 [b][s][1024] (q pre-scaled by 0.125*log2e).  qkvV bf16 [b][512][S].
// S^T C-layout: lane(l31,half) reg r holds key 32mt + 8(r>>2) + 4half + (r&3).
// PV B-frag needs k = 16kk + 8half + j  ->  own g-parity==half groups + partner's
// (lane^32) quarters of the same groups: 8 shfl_xor(32), zero LDS.
__global__ __launch_bounds__(256) void attn_mfma(const u16* __restrict__ qkvT,
                                                 const u16* __restrict__ qkvV,
                                                 u16* __restrict__ houtt) {
    const int b = blockIdx.z, h = blockIdx.y, q0 = blockIdx.x * 128;
    const int tid = threadIdx.x;
    const int lane = tid & 63, w = tid >> 6;
    const int l31 = lane & 31, half = lane >> 5;
    __shared__ u16 ks[2][64 * 64];  // [key][d] chunk-swizzled, double-buffered
    __shared__ u16 vs[2][64 * 64];  // [d][key] chunk-swizzled, double-buffered

    const u16* qrow = qkvT + (size_t)(b * S + q0 + w * 32 + l31) * 1024 + h * HD;
    const u16* krow = qkvT + (size_t)b * S * 1024 + 512 + h * HD;
    const u16* vrow = qkvV + (size_t)(b * 512 + h * HD) * S;

    // Q fragments in registers: B[k][n], n=l31 (query), k = kk*16 + half*8 + j
    bf16x8 qfrag[4];
#pragma unroll
    for (int kk = 0; kk < 4; ++kk)
        qfrag[kk] = *reinterpret_cast<const bf16x8*>(&qrow[kk * 16 + half * 8]);

    // stage K/V tile 0
#pragma unroll
    for (int i = 0; i < 2; ++i) {
        int ci = w * 2 + i;
        int r = ci * 8 + (lane >> 3);
        int c = (lane & 7) ^ (r & 7);
        async_copy16(&krow[(size_t)r * 1024 + c * 8], &ks[0][ci * 512]);
        async_copy16(&vrow[(size_t)r * S + c * 8], &vs[0][ci * 512]);
    }
    __syncthreads();

    f32x16 o_acc[2] = {};
    float l_i = 0.f;

    for (int t = 0; t < 16; ++t) {
        const int cur = t & 1, nxt = cur ^ 1;
        if (t < 15) {
            int kt = (t + 1) * 64;
#pragma unroll
            for (int i = 0; i < 2; ++i) {
                int ci = w * 2 + i;
                int r = ci * 8 + (lane >> 3);
                int c = (lane & 7) ^ (r & 7);
                async_copy16(&krow[(size_t)(kt + r) * 1024 + c * 8], &ks[nxt][ci * 512]);
                async_copy16(&vrow[(size_t)r * S + kt + c * 8], &vs[nxt][ci * 512]);
            }
        }
        // ---- S^T = K Q^T : rows = keys (2 mt halves), cols = 32 queries ----
        f32x16 s_acc[2] = {};
#pragma unroll
        for (int mt = 0; mt < 2; ++mt) {
            int r = mt * 32 + l31;
#pragma unroll
            for (int kk = 0; kk < 4; ++kk) {
                int c8 = kk * 2 + half;
                bf16x8 kf = *reinterpret_cast<const bf16x8*>(
                    &ks[cur][r * 64 + ((c8 ^ (r & 7)) << 3)]);
                s_acc[mt] = __builtin_amdgcn_mfma_f32_32x32x16_bf16(
                    kf, qfrag[kk], s_acc[mt], 0, 0, 0);
            }
        }
        // ---- max-free softmax: p = 2^s; pack into register groups ----
        float rs = 0.f;
        unsigned up[2][4][2];
#pragma unroll
        for (int mt = 0; mt < 2; ++mt)
#pragma unroll
            for (int g = 0; g < 4; ++g) {
                float p0 = __builtin_amdgcn_exp2f(s_acc[mt][g * 4 + 0]);
                float p1 = __builtin_amdgcn_exp2f(s_acc[mt][g * 4 + 1]);
                float p2 = __builtin_amdgcn_exp2f(s_acc[mt][g * 4 + 2]);
                float p3 = __builtin_amdgcn_exp2f(s_acc[mt][g * 4 + 3]);
                rs += (p0 + p1) + (p2 + p3);
                up[mt][g][0] = pack_bf2(p0, p1);
                up[mt][g][1] = pack_bf2(p2, p3);
            }
        l_i += rs;
        // ---- P B-frags via lane^32 quarter exchange (no LDS) ----
        bf16x8 pf[4];
#pragma unroll
        for (int mt = 0; mt < 2; ++mt)
#pragma unroll
            for (int jj = 0; jj < 2; ++jj) {
                // send the group the partner needs (g parity = 1-half)
                unsigned s0v = half ? up[mt][2 * jj][0] : up[mt][2 * jj + 1][0];
                unsigned s1v = half ? up[mt][2 * jj][1] : up[mt][2 * jj + 1][1];
                unsigned r0 = __shfl_xor((int)s0v, 32, 64);
                unsigned r1 = __shfl_xor((int)s1v, 32, 64);
                // keep own group (g parity = half)
                unsigned m0 = half ? up[mt][2 * jj + 1][0] : up[mt][2 * jj][0];
                unsigned m1 = half ? up[mt][2 * jj + 1][1] : up[mt][2 * jj][1];
                union { unsigned u4[4]; bf16x8 v; } q;
                q.u4[0] = half ? r0 : m0;  // keys base+0..3 (quarter hh=0)
                q.u4[1] = half ? r1 : m1;
                q.u4[2] = half ? m0 : r0;  // keys base+4..7 (quarter hh=1)
                q.u4[3] = half ? m1 : r1;
                pf[mt * 2 + jj] = q.v;
            }
        // ---- O^T += V^T P^T : rows = d (2 nt halves), cols = 32 queries ----
#pragma unroll
        for (int nt = 0; nt < 2; ++nt) {
            int rv = nt * 32 + l31;
#pragma unroll
            for (int kk = 0; kk < 4; ++kk) {
                int c8 = kk * 2 + half;
                bf16x8 vf = *reinterpret_cast<const bf16x8*>(
                    &vs[cur][rv * 64 + ((c8 ^ (rv & 7)) << 3)]);
                o_acc[nt] = __builtin_amdgcn_mfma_f32_32x32x16_bf16(
                    vf, pf[kk], o_acc[nt], 0, 0, 0);
            }
        }
        __syncthreads();  // drains prefetch DMAs; next tile ready
    }
    // lanes l31 and l31+32 hold complementary key subsets; combine denominators
    l_i += __shfl_xor(l_i, 32, 64);
    float inv = 1.f / l_i;
    u16* orow = houtt + (size_t)(b * S + q0 + w * 32 + l31) * 512 + h * HD;
#pragma unroll
    for (int nt = 0; nt < 2; ++nt)
#pragma unroll
        for (int g = 0; g < 4; ++g) {
            uint2 pk;
            pk.x = pack_bf2(o_acc[nt][g * 4 + 0] * inv, o_acc[nt][g * 4 + 1] * inv);
            pk.y = pack_bf2(o_acc[nt][g * 4 + 2] * inv, o_acc[nt][g * 4 + 3] * inv);
            // d = nt*32 + 8g + 4*half + [0..3]
            *reinterpret_cast<uint2*>(&orow[nt * 32 + g * 8 + half * 4]) = pk;
        }
}

extern "C" void kernel_launch(void* const* d_in, const int* in_sizes, int n_in,
                              void* d_out, int out_size, void* d_ws, size_t ws_size,
                              hipStream_t stream) {
    const float* x      = (const float*)d_in[0];
    const float* gamma  = (const float*)d_in[1];
    const float* beta   = (const float*)d_in[2];
    const float* w_qkv  = (const float*)d_in[3];
    const float* b_qkv  = (const float*)d_in[4];
    const float* w_proj = (const float*)d_in[5];
    const float* b_proj = (const float*)d_in[6];
    float* out = (float*)d_out;

    char* ws = (char*)d_ws;
    float* stats = (float*)ws;                                     // 4 KB
    u16* wbf   = (u16*)(ws + 4096);                                // 2 MB (qkv+proj bf16)
    u16* xnt   = (u16*)(ws + 4096 + 2097152);                      // 8 MB [b][s][512]
    u16* qkvT  = (u16*)(ws + 4096 + 2097152 + 8388608);            // 16 MB [b][s][1024]
    u16* qkvV  = (u16*)(ws + 4096 + 2097152 + 8388608 + 16777216); // 8 MB [b][512][S]
    u16* houtt = xnt;  // alias: xnt dead after qkv GEMM

    prep<<<1280, 256, 0, stream>>>(x, w_qkv, w_proj, stats, wbf);
    gn_apply_t<<<dim3(16, 8, Bn), 256, 0, stream>>>(x, gamma, beta, stats, xnt);
    mfma_gemm<0><<<dim3(8, 12, Bn), 256, 0, stream>>>(
        wbf, xnt, b_qkv, nullptr, qkvT, qkvV, nullptr);
    attn_mfma<<<dim3(8, NH, Bn), 256, 0, stream>>>(qkvT, qkvV, houtt);  // 8 = S/128
    mfma_gemm<1><<<dim3(8, 4, Bn), 256, 0, stream>>>(
        wbf + 1536 * 512, houtt, b_proj, x, nullptr, nullptr, out);
}

// Round 10
// 166.468 us; speedup vs baseline: 1.0407x; 1.0407x over previous
//
#include <hip/hip_runtime.h>
#include <hip/hip_bf16.h>

typedef __hip_bfloat16 bf16;
typedef unsigned short u16;
typedef __attribute__((ext_vector_type(8))) short bf16x8;
typedef __attribute__((ext_vector_type(4))) float f32x4;
typedef __attribute__((ext_vector_type(16))) float f32x16;

static constexpr int Bn = 8;
static constexpr int C = 512;
static constexpr int S = 1024;
static constexpr int NH = 8;
static constexpr int HD = 64;
static constexpr int CPG = 16;
#define EPSV 1e-5f
#define QSCALE 0.18033688011112042f  /* 0.125 * log2(e): folds attn scale + exp->exp2 */

__device__ __forceinline__ u16 f2bf(float f) {
    bf16 h = __float2bfloat16(f);
    return *reinterpret_cast<u16*>(&h);
}
__device__ __forceinline__ unsigned pack_bf2(float a, float b) {
    __hip_bfloat162 h = __float22bfloat162_rn(make_float2(a, b));
    return *reinterpret_cast<unsigned*>(&h);
}

// async global->LDS, 16B per lane; LDS dest = wave-uniform base + lane*16
__device__ __forceinline__ void async_copy16(const void* g, void* l) {
    __builtin_amdgcn_global_load_lds(
        (const __attribute__((address_space(1))) void*)g,
        (__attribute__((address_space(3))) void*)l, 16, 0, 0);
}

// ---- prep: blocks 0-255 GroupNorm stats; blocks 256-1279 weight fp32->bf16 ----
__global__ __launch_bounds__(256) void prep(const float* __restrict__ x,
                                            const float* __restrict__ wqkv,
                                            const float* __restrict__ wproj,
                                            float* __restrict__ stats,
                                            u16* __restrict__ wbf) {
    const int tid = threadIdx.x;
    if (blockIdx.x < 256) {
        const int bg = blockIdx.x;
        const size_t base = (size_t)bg * CPG * S;
        const int N = CPG * S;  // 16384
        float sum = 0.f, sq = 0.f;
        for (int i = tid * 4; i < N; i += 1024) {
            float4 v = *reinterpret_cast<const float4*>(&x[base + i]);
            sum += v.x + v.y + v.z + v.w;
            sq += v.x * v.x + v.y * v.y + v.z * v.z + v.w * v.w;
        }
#pragma unroll
        for (int off = 32; off > 0; off >>= 1) {
            sum += __shfl_down(sum, off, 64);
            sq  += __shfl_down(sq,  off, 64);
        }
        __shared__ float s0[4], s1[4];
        if ((tid & 63) == 0) { s0[tid >> 6] = sum; s1[tid >> 6] = sq; }
        __syncthreads();
        if (tid == 0) {
            float a  = s0[0] + s0[1] + s0[2] + s0[3];
            float b2 = s1[0] + s1[1] + s1[2] + s1[3];
            float mu = a / (float)N;
            float var = fmaxf(b2 / (float)N - mu * mu, 0.f);
            stats[bg] = mu;
            stats[256 + bg] = rsqrtf(var + EPSV);
        }
    } else {
        int idx = (blockIdx.x - 256) * 1024 + tid * 4;  // 2048*512 total
        float4 v;
        float sc = 1.f;
        if (idx < 1536 * 512) {
            v = *reinterpret_cast<const float4*>(&wqkv[idx]);
            if (idx < 512 * 512) sc = QSCALE;  // Q rows
        } else {
            v = *reinterpret_cast<const float4*>(&wproj[idx - 1536 * 512]);
        }
        u16 t[4] = {f2bf(v.x * sc), f2bf(v.y * sc), f2bf(v.z * sc), f2bf(v.w * sc)};
        *reinterpret_cast<uint2*>(&wbf[idx]) = *reinterpret_cast<uint2*>(t);
    }
}

// ------- GN apply + transpose: x[b][c][s] fp32 -> xnt[b][s][c] bf16 -------
__global__ __launch_bounds__(256) void gn_apply_t(const float* __restrict__ x,
                                                  const float* __restrict__ gamma,
                                                  const float* __restrict__ beta,
                                                  const float* __restrict__ stats,
                                                  u16* __restrict__ xnt) {
    const int b = blockIdx.z, c0 = blockIdx.y * 64, s0 = blockIdx.x * 64;
    const int tid = threadIdx.x;
    __shared__ u16 T[64 * 72];
    const float* xb = x + ((size_t)b * C + c0) * S;
#pragma unroll
    for (int i = 0; i < 4; ++i) {
        int ch = i * 256 + tid;
        int c = ch >> 4, seg = ch & 15;
        int cg = c0 + c;
        float mu = stats[b * 32 + (cg >> 4)];
        float rstd = stats[256 + b * 32 + (cg >> 4)];
        float ga = gamma[cg], be = beta[cg];
        float4 v = *reinterpret_cast<const float4*>(&xb[(size_t)c * S + s0 + seg * 4]);
        float vals[4] = {v.x, v.y, v.z, v.w};
#pragma unroll
        for (int j = 0; j < 4; ++j)
            T[(seg * 4 + j) * 72 + c] = f2bf((vals[j] - mu) * rstd * ga + be);
    }
    __syncthreads();
#pragma unroll
    for (int i = 0; i < 2; ++i) {
        int ch = i * 256 + tid;
        int r = ch >> 3, seg = ch & 7;
        uint4 val = *reinterpret_cast<const uint4*>(&T[r * 72 + seg * 8]);
        *reinterpret_cast<uint4*>(&xnt[(size_t)(b * S + s0 + r) * C + c0 + seg * 8]) = val;
    }
}

// ---- MFMA GEMM (round-7 config: BK=64, single-buffer, two barriers/iter) ----
// A from pre-converted bf16 weights Wb (DMA). Xt bf16 [b][s][512] k-contiguous.
// MODE 0 (qkv): o<1024 (q,k) -> qkvT[b][s][1024] transposed; o>=1024 (v) -> qkvV.
// MODE 1 (proj): fp32 output + residual.
template <int MODE>
__global__ __launch_bounds__(256) void mfma_gemm(const u16* __restrict__ Wb,
                                                 const u16* __restrict__ Xt,
                                                 const float* __restrict__ bias,
                                                 const float* __restrict__ resid,
                                                 u16* __restrict__ qkvT,
                                                 u16* __restrict__ qkvV,
                                                 float* __restrict__ Yf) {
    const int K = 512;
    const int b = blockIdx.z, o0 = blockIdx.y * 128, s0 = blockIdx.x * 128;
    const int tid = threadIdx.x;
    const int lane = tid & 63, w = tid >> 6;
    const int quad = lane >> 4, l15 = lane & 15;
    const int wr = w >> 1, wc = w & 1;
    __shared__ u16 As[128 * 64];  // [o][k-chunk]: chunk c at slot c^(row&7)
    __shared__ u16 Bs[128 * 64];
    f32x4 acc[4][4] = {};
    const u16* Xb = Xt + (size_t)(b * S + s0) * K;
    for (int k0 = 0; k0 < K; k0 += 64) {
#pragma unroll
        for (int i = 0; i < 4; ++i) {
            int ci = w * 4 + i;
            int r = ci * 8 + (lane >> 3);
            int c = (lane & 7) ^ (r & 7);
            async_copy16(&Wb[(size_t)(o0 + r) * K + k0 + c * 8], &As[ci * 512]);
            async_copy16(&Xb[(size_t)r * K + k0 + c * 8], &Bs[ci * 512]);
        }
        __syncthreads();
#pragma unroll
        for (int kk = 0; kk < 2; ++kk) {
            bf16x8 af[4], bfr[4];
#pragma unroll
            for (int mt = 0; mt < 4; ++mt) {
                int R = wr * 64 + mt * 16 + l15;
                af[mt] = *reinterpret_cast<const bf16x8*>(
                    &As[R * 64 + (((kk * 4 + quad) ^ (R & 7)) << 3)]);
            }
#pragma unroll
            for (int nt = 0; nt < 4; ++nt) {
                int R = wc * 64 + nt * 16 + l15;
                bfr[nt] = *reinterpret_cast<const bf16x8*>(
                    &Bs[R * 64 + (((kk * 4 + quad) ^ (R & 7)) << 3)]);
            }
#pragma unroll
            for (int mt = 0; mt < 4; ++mt)
#pragma unroll
                for (int nt = 0; nt < 4; ++nt)
                    acc[mt][nt] = __builtin_amdgcn_mfma_f32_16x16x32_bf16(
                        af[mt], bfr[nt], acc[mt][nt], 0, 0, 0);
        }
        __syncthreads();
    }
    if (MODE == 1) {
#pragma unroll
        for (int mt = 0; mt < 4; ++mt) {
#pragma unroll
            for (int reg = 0; reg < 4; ++reg) {
                int o = o0 + wr * 64 + mt * 16 + quad * 4 + reg;
                float bz = bias[o];
#pragma unroll
                for (int nt = 0; nt < 4; ++nt) {
                    int s = s0 + wc * 64 + nt * 16 + l15;
                    size_t idx = (size_t)(b * C + o) * S + s;
                    Yf[idx] = acc[mt][nt][reg] + bz + resid[idx];
                }
            }
        }
    } else if (o0 < 1024) {
        // q,k -> [b][s][1024]; q bias gets QSCALE (matches pre-scaled Q weights)
        float bsc = (o0 < 512) ? QSCALE : 1.f;
#pragma unroll
        for (int mt = 0; mt < 4; ++mt) {
            int o_b = o0 + wr * 64 + mt * 16 + quad * 4;
            float bz[4];
#pragma unroll
            for (int reg = 0; reg < 4; ++reg) bz[reg] = bias[o_b + reg] * bsc;
#pragma unroll
            for (int nt = 0; nt < 4; ++nt) {
                int s = s0 + wc * 64 + nt * 16 + l15;
                uint2 pk;
                pk.x = pack_bf2(acc[mt][nt][0] + bz[0], acc[mt][nt][1] + bz[1]);
                pk.y = pack_bf2(acc[mt][nt][2] + bz[2], acc[mt][nt][3] + bz[3]);
                *reinterpret_cast<uint2*>(&qkvT[(size_t)(b * S + s) * 1024 + o_b]) = pk;
            }
        }
    } else {
        // v -> [b][v-channel][S]
#pragma unroll
        for (int mt = 0; mt < 4; ++mt) {
#pragma unroll
            for (int reg = 0; reg < 4; ++reg) {
                int o = o0 - 1024 + wr * 64 + mt * 16 + quad * 4 + reg;
                float bz = bias[o + 1024];
#pragma unroll
                for (int nt = 0; nt < 4; ++nt) {
                    int s = s0 + wc * 64 + nt * 16 + l15;
                    qkvV[(size_t)(b * 512 + o) * S + s] = f2bf(acc[mt][nt][reg] + bz);
                }
            }
        }
    }
}

// ---- MFMA flash attention v3: 32x32x16, Q in regs, P in regs (xor-32 swap) ----
// qkvT bf16 [b][s][1024] (q pre-scaled by 0.125*log2e).  qkvV bf16 [b][512][S].
// S^T C-layout: lane(l31,half) reg r holds key 32mt + 8(r>>2) + 4half + (r&3).
// PV B-frag needs k = 16kk + 8half + j  ->  own g-parity==half groups + partner's
// (lane^32) quarters of the same groups: 8 shfl_xor(32), zero LDS.
__global__ __launch_bounds__(256) void attn_mfma(const u16* __restrict__ qkvT,
                                                 const u16* __restrict__ qkvV,
                                                 u16* __restrict__ houtt) {
    const int b = blockIdx.z, h = blockIdx.y, q0 = blockIdx.x * 128;
    const int tid = threadIdx.x;
    const int lane = tid & 63, w = tid >> 6;
    const int l31 = lane & 31, half = lane >> 5;
    __shared__ u16 ks[2][64 * 64];  // [key][d] chunk-swizzled, double-buffered
    __shared__ u16 vs[2][64 * 64];  // [d][key] chunk-swizzled, double-buffered

    const u16* qrow = qkvT + (size_t)(b * S + q0 + w * 32 + l31) * 1024 + h * HD;
    const u16* krow = qkvT + (size_t)b * S * 1024 + 512 + h * HD;
    const u16* vrow = qkvV + (size_t)(b * 512 + h * HD) * S;

    // Q fragments in registers: B[k][n], n=l31 (query), k = kk*16 + half*8 + j
    bf16x8 qfrag[4];
#pragma unroll
    for (int kk = 0; kk < 4; ++kk)
        qfrag[kk] = *reinterpret_cast<const bf16x8*>(&qrow[kk * 16 + half * 8]);

    // stage K/V tile 0
#pragma unroll
    for (int i = 0; i < 2; ++i) {
        int ci = w * 2 + i;
        int r = ci * 8 + (lane >> 3);
        int c = (lane & 7) ^ (r & 7);
        async_copy16(&krow[(size_t)r * 1024 + c * 8], &ks[0][ci * 512]);
        async_copy16(&vrow[(size_t)r * S + c * 8], &vs[0][ci * 512]);
    }
    __syncthreads();

    f32x16 o_acc[2] = {};
    float l_i = 0.f;

    for (int t = 0; t < 16; ++t) {
        const int cur = t & 1, nxt = cur ^ 1;
        if (t < 15) {
            int kt = (t + 1) * 64;
#pragma unroll
            for (int i = 0; i < 2; ++i) {
                int ci = w * 2 + i;
                int r = ci * 8 + (lane >> 3);
                int c = (lane & 7) ^ (r & 7);
                async_copy16(&krow[(size_t)(kt + r) * 1024 + c * 8], &ks[nxt][ci * 512]);
                async_copy16(&vrow[(size_t)r * S + kt + c * 8], &vs[nxt][ci * 512]);
            }
        }
        // ---- S^T = K Q^T : rows = keys (2 mt halves), cols = 32 queries ----
        f32x16 s_acc[2] = {};
#pragma unroll
        for (int mt = 0; mt < 2; ++mt) {
            int r = mt * 32 + l31;
#pragma unroll
            for (int kk = 0; kk < 4; ++kk) {
                int c8 = kk * 2 + half;
                bf16x8 kf = *reinterpret_cast<const bf16x8*>(
                    &ks[cur][r * 64 + ((c8 ^ (r & 7)) << 3)]);
                s_acc[mt] = __builtin_amdgcn_mfma_f32_32x32x16_bf16(
                    kf, qfrag[kk], s_acc[mt], 0, 0, 0);
            }
        }
        // ---- max-free softmax: p = 2^s; pack into register groups ----
        float rs = 0.f;
        unsigned up[2][4][2];
#pragma unroll
        for (int mt = 0; mt < 2; ++mt)
#pragma unroll
            for (int g = 0; g < 4; ++g) {
                float p0 = __builtin_amdgcn_exp2f(s_acc[mt][g * 4 + 0]);
                float p1 = __builtin_amdgcn_exp2f(s_acc[mt][g * 4 + 1]);
                float p2 = __builtin_amdgcn_exp2f(s_acc[mt][g * 4 + 2]);
                float p3 = __builtin_amdgcn_exp2f(s_acc[mt][g * 4 + 3]);
                rs += (p0 + p1) + (p2 + p3);
                up[mt][g][0] = pack_bf2(p0, p1);
                up[mt][g][1] = pack_bf2(p2, p3);
            }
        l_i += rs;
        // ---- P B-frags via lane^32 quarter exchange (no LDS) ----
        bf16x8 pf[4];
#pragma unroll
        for (int mt = 0; mt < 2; ++mt)
#pragma unroll
            for (int jj = 0; jj < 2; ++jj) {
                // send the group the partner needs (g parity = 1-half)
                unsigned s0v = half ? up[mt][2 * jj][0] : up[mt][2 * jj + 1][0];
                unsigned s1v = half ? up[mt][2 * jj][1] : up[mt][2 * jj + 1][1];
                unsigned r0 = __shfl_xor((int)s0v, 32, 64);
                unsigned r1 = __shfl_xor((int)s1v, 32, 64);
                // keep own group (g parity = half)
                unsigned m0 = half ? up[mt][2 * jj + 1][0] : up[mt][2 * jj][0];
                unsigned m1 = half ? up[mt][2 * jj + 1][1] : up[mt][2 * jj][1];
                union { unsigned u4[4]; bf16x8 v; } q;
                q.u4[0] = half ? r0 : m0;  // keys base+0..3 (quarter hh=0)
                q.u4[1] = half ? r1 : m1;
                q.u4[2] = half ? m0 : r0;  // keys base+4..7 (quarter hh=1)
                q.u4[3] = half ? m1 : r1;
                pf[mt * 2 + jj] = q.v;
            }
        // ---- O^T += V^T P^T : rows = d (2 nt halves), cols = 32 queries ----
#pragma unroll
        for (int nt = 0; nt < 2; ++nt) {
            int rv = nt * 32 + l31;
#pragma unroll
            for (int kk = 0; kk < 4; ++kk) {
                int c8 = kk * 2 + half;
                bf16x8 vf = *reinterpret_cast<const bf16x8*>(
                    &vs[cur][rv * 64 + ((c8 ^ (rv & 7)) << 3)]);
                o_acc[nt] = __builtin_amdgcn_mfma_f32_32x32x16_bf16(
                    vf, pf[kk], o_acc[nt], 0, 0, 0);
            }
        }
        __syncthreads();  // drains prefetch DMAs; next tile ready
    }
    // lanes l31 and l31+32 hold complementary key subsets; combine denominators
    l_i += __shfl_xor(l_i, 32, 64);
    float inv = 1.f / l_i;
    u16* orow = houtt + (size_t)(b * S + q0 + w * 32 + l31) * 512 + h * HD;
#pragma unroll
    for (int nt = 0; nt < 2; ++nt)
#pragma unroll
        for (int g = 0; g < 4; ++g) {
            uint2 pk;
            pk.x = pack_bf2(o_acc[nt][g * 4 + 0] * inv, o_acc[nt][g * 4 + 1] * inv);
            pk.y = pack_bf2(o_acc[nt][g * 4 + 2] * inv, o_acc[nt][g * 4 + 3] * inv);
            // d = nt*32 + 8g + 4*half + [0..3]
            *reinterpret_cast<uint2*>(&orow[nt * 32 + g * 8 + half * 4]) = pk;
        }
}

extern "C" void kernel_launch(void* const* d_in, const int* in_sizes, int n_in,
                              void* d_out, int out_size, void* d_ws, size_t ws_size,
                              hipStream_t stream) {
    const float* x      = (const float*)d_in[0];
    const float* gamma  = (const float*)d_in[1];
    const float* beta   = (const float*)d_in[2];
    const float* w_qkv  = (const float*)d_in[3];
    const float* b_qkv  = (const float*)d_in[4];
    const float* w_proj = (const float*)d_in[5];
    const float* b_proj = (const float*)d_in[6];
    float* out = (float*)d_out;

    char* ws = (char*)d_ws;
    float* stats = (float*)ws;                                     // 4 KB
    u16* wbf   = (u16*)(ws + 4096);                                // 2 MB (qkv+proj bf16)
    u16* xnt   = (u16*)(ws + 4096 + 2097152);                      // 8 MB [b][s][512]
    u16* qkvT  = (u16*)(ws + 4096 + 2097152 + 8388608);            // 16 MB [b][s][1024]
    u16* qkvV  = (u16*)(ws + 4096 + 2097152 + 8388608 + 16777216); // 8 MB [b][512][S]
    u16* houtt = xnt;  // alias: xnt dead after qkv GEMM

    prep<<<1280, 256, 0, stream>>>(x, w_qkv, w_proj, stats, wbf);
    gn_apply_t<<<dim3(16, 8, Bn), 256, 0, stream>>>(x, gamma, beta, stats, xnt);
    mfma_gemm<0><<<dim3(8, 12, Bn), 256, 0, stream>>>(
        wbf, xnt, b_qkv, nullptr, qkvT, qkvV, nullptr);
    attn_mfma<<<dim3(8, NH, Bn), 256, 0, stream>>>(qkvT, qkvV, houtt);  // 8 = S/128
    mfma_gemm<1><<<dim3(8, 4, Bn), 256, 0, stream>>>(
        wbf + 1536 * 512, houtt, b_proj, x, nullptr, nullptr, out);
}

// Round 11
// 156.094 us; speedup vs baseline: 1.1098x; 1.0665x over previous
//
#include <hip/hip_runtime.h>
#include <hip/hip_bf16.h>

typedef __hip_bfloat16 bf16;
typedef unsigned short u16;
typedef __attribute__((ext_vector_type(8))) short bf16x8;
typedef __attribute__((ext_vector_type(4))) float f32x4;
typedef __attribute__((ext_vector_type(16))) float f32x16;

static constexpr int Bn = 8;
static constexpr int C = 512;
static constexpr int S = 1024;
static constexpr int NH = 8;
static constexpr int HD = 64;
static constexpr int CPG = 16;
#define EPSV 1e-5f
#define QSCALE 0.18033688011112042f  /* 0.125 * log2(e): folds attn scale + exp->exp2 */

__device__ __forceinline__ u16 f2bf(float f) {
    bf16 h = __float2bfloat16(f);
    return *reinterpret_cast<u16*>(&h);
}
__device__ __forceinline__ unsigned pack_bf2(float a, float b) {
    __hip_bfloat162 h = __float22bfloat162_rn(make_float2(a, b));
    return *reinterpret_cast<unsigned*>(&h);
}

// async global->LDS, 16B per lane; LDS dest = wave-uniform base + lane*16
__device__ __forceinline__ void async_copy16(const void* g, void* l) {
    __builtin_amdgcn_global_load_lds(
        (const __attribute__((address_space(1))) void*)g,
        (__attribute__((address_space(3))) void*)l, 16, 0, 0);
}

// ---- prep: blocks 0-255 GroupNorm stats; blocks 256-1279 weight fp32->bf16 ----
__global__ __launch_bounds__(256) void prep(const float* __restrict__ x,
                                            const float* __restrict__ wqkv,
                                            const float* __restrict__ wproj,
                                            float* __restrict__ stats,
                                            u16* __restrict__ wbf) {
    const int tid = threadIdx.x;
    if (blockIdx.x < 256) {
        const int bg = blockIdx.x;
        const size_t base = (size_t)bg * CPG * S;
        const int N = CPG * S;  // 16384
        float sum = 0.f, sq = 0.f;
        for (int i = tid * 4; i < N; i += 1024) {
            float4 v = *reinterpret_cast<const float4*>(&x[base + i]);
            sum += v.x + v.y + v.z + v.w;
            sq += v.x * v.x + v.y * v.y + v.z * v.z + v.w * v.w;
        }
#pragma unroll
        for (int off = 32; off > 0; off >>= 1) {
            sum += __shfl_down(sum, off, 64);
            sq  += __shfl_down(sq,  off, 64);
        }
        __shared__ float s0[4], s1[4];
        if ((tid & 63) == 0) { s0[tid >> 6] = sum; s1[tid >> 6] = sq; }
        __syncthreads();
        if (tid == 0) {
            float a  = s0[0] + s0[1] + s0[2] + s0[3];
            float b2 = s1[0] + s1[1] + s1[2] + s1[3];
            float mu = a / (float)N;
            float var = fmaxf(b2 / (float)N - mu * mu, 0.f);
            stats[bg] = mu;
            stats[256 + bg] = rsqrtf(var + EPSV);
        }
    } else {
        int idx = (blockIdx.x - 256) * 1024 + tid * 4;  // 2048*512 total
        float4 v;
        float sc = 1.f;
        if (idx < 1536 * 512) {
            v = *reinterpret_cast<const float4*>(&wqkv[idx]);
            if (idx < 512 * 512) sc = QSCALE;  // Q rows
        } else {
            v = *reinterpret_cast<const float4*>(&wproj[idx - 1536 * 512]);
        }
        u16 t[4] = {f2bf(v.x * sc), f2bf(v.y * sc), f2bf(v.z * sc), f2bf(v.w * sc)};
        *reinterpret_cast<uint2*>(&wbf[idx]) = *reinterpret_cast<uint2*>(t);
    }
}

// ------- GN apply + transpose: x[b][c][s] fp32 -> xnt[b][s][c] bf16 -------
__global__ __launch_bounds__(256) void gn_apply_t(const float* __restrict__ x,
                                                  const float* __restrict__ gamma,
                                                  const float* __restrict__ beta,
                                                  const float* __restrict__ stats,
                                                  u16* __restrict__ xnt) {
    const int b = blockIdx.z, c0 = blockIdx.y * 64, s0 = blockIdx.x * 64;
    const int tid = threadIdx.x;
    __shared__ u16 T[64 * 72];
    const float* xb = x + ((size_t)b * C + c0) * S;
#pragma unroll
    for (int i = 0; i < 4; ++i) {
        int ch = i * 256 + tid;
        int c = ch >> 4, seg = ch & 15;
        int cg = c0 + c;
        float mu = stats[b * 32 + (cg >> 4)];
        float rstd = stats[256 + b * 32 + (cg >> 4)];
        float ga = gamma[cg], be = beta[cg];
        float4 v = *reinterpret_cast<const float4*>(&xb[(size_t)c * S + s0 + seg * 4]);
        float vals[4] = {v.x, v.y, v.z, v.w};
#pragma unroll
        for (int j = 0; j < 4; ++j)
            T[(seg * 4 + j) * 72 + c] = f2bf((vals[j] - mu) * rstd * ga + be);
    }
    __syncthreads();
#pragma unroll
    for (int i = 0; i < 2; ++i) {
        int ch = i * 256 + tid;
        int r = ch >> 3, seg = ch & 7;
        uint4 val = *reinterpret_cast<const uint4*>(&T[r * 72 + seg * 8]);
        *reinterpret_cast<uint4*>(&xnt[(size_t)(b * S + s0 + r) * C + c0 + seg * 8]) = val;
    }
}

// ---- MFMA GEMM (round-7 config: BK=64, single-buffer, two barriers/iter) ----
// A from pre-converted bf16 weights Wb (DMA). Xt bf16 [b][s][512] k-contiguous.
// MODE 0 (qkv): o<1024 (q,k) -> qkvT[b][s][1024] transposed; o>=1024 (v) -> qkvV.
// MODE 1 (proj): fp32 output + residual.
template <int MODE>
__global__ __launch_bounds__(256) void mfma_gemm(const u16* __restrict__ Wb,
                                                 const u16* __restrict__ Xt,
                                                 const float* __restrict__ bias,
                                                 const float* __restrict__ resid,
                                                 u16* __restrict__ qkvT,
                                                 u16* __restrict__ qkvV,
                                                 float* __restrict__ Yf) {
    const int K = 512;
    const int b = blockIdx.z, o0 = blockIdx.y * 128, s0 = blockIdx.x * 128;
    const int tid = threadIdx.x;
    const int lane = tid & 63, w = tid >> 6;
    const int quad = lane >> 4, l15 = lane & 15;
    const int wr = w >> 1, wc = w & 1;
    __shared__ u16 As[128 * 64];  // [o][k-chunk]: chunk c at slot c^(row&7)
    __shared__ u16 Bs[128 * 64];
    f32x4 acc[4][4] = {};
    const u16* Xb = Xt + (size_t)(b * S + s0) * K;
    for (int k0 = 0; k0 < K; k0 += 64) {
#pragma unroll
        for (int i = 0; i < 4; ++i) {
            int ci = w * 4 + i;
            int r = ci * 8 + (lane >> 3);
            int c = (lane & 7) ^ (r & 7);
            async_copy16(&Wb[(size_t)(o0 + r) * K + k0 + c * 8], &As[ci * 512]);
            async_copy16(&Xb[(size_t)r * K + k0 + c * 8], &Bs[ci * 512]);
        }
        __syncthreads();
#pragma unroll
        for (int kk = 0; kk < 2; ++kk) {
            bf16x8 af[4], bfr[4];
#pragma unroll
            for (int mt = 0; mt < 4; ++mt) {
                int R = wr * 64 + mt * 16 + l15;
                af[mt] = *reinterpret_cast<const bf16x8*>(
                    &As[R * 64 + (((kk * 4 + quad) ^ (R & 7)) << 3)]);
            }
#pragma unroll
            for (int nt = 0; nt < 4; ++nt) {
                int R = wc * 64 + nt * 16 + l15;
                bfr[nt] = *reinterpret_cast<const bf16x8*>(
                    &Bs[R * 64 + (((kk * 4 + quad) ^ (R & 7)) << 3)]);
            }
#pragma unroll
            for (int mt = 0; mt < 4; ++mt)
#pragma unroll
                for (int nt = 0; nt < 4; ++nt)
                    acc[mt][nt] = __builtin_amdgcn_mfma_f32_16x16x32_bf16(
                        af[mt], bfr[nt], acc[mt][nt], 0, 0, 0);
        }
        __syncthreads();
    }
    if (MODE == 1) {
#pragma unroll
        for (int mt = 0; mt < 4; ++mt) {
#pragma unroll
            for (int reg = 0; reg < 4; ++reg) {
                int o = o0 + wr * 64 + mt * 16 + quad * 4 + reg;
                float bz = bias[o];
#pragma unroll
                for (int nt = 0; nt < 4; ++nt) {
                    int s = s0 + wc * 64 + nt * 16 + l15;
                    size_t idx = (size_t)(b * C + o) * S + s;
                    Yf[idx] = acc[mt][nt][reg] + bz + resid[idx];
                }
            }
        }
    } else if (o0 < 1024) {
        // q,k -> [b][s][1024]; q bias gets QSCALE (matches pre-scaled Q weights)
        float bsc = (o0 < 512) ? QSCALE : 1.f;
#pragma unroll
        for (int mt = 0; mt < 4; ++mt) {
            int o_b = o0 + wr * 64 + mt * 16 + quad * 4;
            float bz[4];
#pragma unroll
            for (int reg = 0; reg < 4; ++reg) bz[reg] = bias[o_b + reg] * bsc;
#pragma unroll
            for (int nt = 0; nt < 4; ++nt) {
                int s = s0 + wc * 64 + nt * 16 + l15;
                uint2 pk;
                pk.x = pack_bf2(acc[mt][nt][0] + bz[0], acc[mt][nt][1] + bz[1]);
                pk.y = pack_bf2(acc[mt][nt][2] + bz[2], acc[mt][nt][3] + bz[3]);
                *reinterpret_cast<uint2*>(&qkvT[(size_t)(b * S + s) * 1024 + o_b]) = pk;
            }
        }
    } else {
        // v -> [b][v-channel][S]
#pragma unroll
        for (int mt = 0; mt < 4; ++mt) {
#pragma unroll
            for (int reg = 0; reg < 4; ++reg) {
                int o = o0 - 1024 + wr * 64 + mt * 16 + quad * 4 + reg;
                float bz = bias[o + 1024];
#pragma unroll
                for (int nt = 0; nt < 4; ++nt) {
                    int s = s0 + wc * 64 + nt * 16 + l15;
                    qkvV[(size_t)(b * 512 + o) * S + s] = f2bf(acc[mt][nt][reg] + bz);
                }
            }
        }
    }
}

// ---- MFMA flash attention (round-7 v2): 128-query blocks, 32x32x16, P via LDS --
// Grid swizzle: blockIdx.x = b*8+h (stride-64 blocks share (b,h) -> same XCD),
// blockIdx.y = q-block.  qkvT bf16 [b][s][1024], qkvV bf16 [b][512][S].
// 32x32 C/D: col=lane&31, row=(reg&3)+8*(reg>>2)+4*(lane>>5)  [m74/m101]
__global__ __launch_bounds__(256) void attn_mfma(const u16* __restrict__ qkvT,
                                                 const u16* __restrict__ qkvV,
                                                 u16* __restrict__ houtt) {
    const int b = blockIdx.x >> 3, h = blockIdx.x & 7, q0 = blockIdx.y * 128;
    const int tid = threadIdx.x;
    const int lane = tid & 63, w = tid >> 6;
    const int l31 = lane & 31, half = lane >> 5;
    __shared__ u16 ks[2][64 * 64];  // [key][d] chunk-swizzled, double-buffered
    __shared__ u16 vs[2][64 * 64];  // [d][key] chunk-swizzled, double-buffered
    __shared__ u16 ps[128 * 68];    // [q][key] stride 68: 2-way banks, 8B-aligned

    const u16* qrow = qkvT + (size_t)(b * S + q0 + w * 32 + l31) * 1024 + h * HD;
    const u16* krow = qkvT + (size_t)b * S * 1024 + 512 + h * HD;
    const u16* vrow = qkvV + (size_t)(b * 512 + h * HD) * S;

    // Q fragments in registers: B[k][n], n=l31 (query), k = kk*16 + half*8 + j
    bf16x8 qfrag[4];
#pragma unroll
    for (int kk = 0; kk < 4; ++kk)
        qfrag[kk] = *reinterpret_cast<const bf16x8*>(&qrow[kk * 16 + half * 8]);

    // stage K/V tile 0
#pragma unroll
    for (int i = 0; i < 2; ++i) {
        int ci = w * 2 + i;
        int r = ci * 8 + (lane >> 3);
        int c = (lane & 7) ^ (r & 7);
        async_copy16(&krow[(size_t)r * 1024 + c * 8], &ks[0][ci * 512]);
        async_copy16(&vrow[(size_t)r * S + c * 8], &vs[0][ci * 512]);
    }
    __syncthreads();

    f32x16 o_acc[2] = {};
    float l_i = 0.f;
    const int prow = (w * 32 + l31) * 68;  // this lane's P row (wave-private)

    for (int t = 0; t < 16; ++t) {
        const int cur = t & 1, nxt = cur ^ 1;
        if (t < 15) {
            int kt = (t + 1) * 64;
#pragma unroll
            for (int i = 0; i < 2; ++i) {
                int ci = w * 2 + i;
                int r = ci * 8 + (lane >> 3);
                int c = (lane & 7) ^ (r & 7);
                async_copy16(&krow[(size_t)(kt + r) * 1024 + c * 8], &ks[nxt][ci * 512]);
                async_copy16(&vrow[(size_t)r * S + kt + c * 8], &vs[nxt][ci * 512]);
            }
        }
        // ---- S^T = K Q^T : rows = keys (2 mt halves), cols = 32 queries ----
        f32x16 s_acc[2] = {};
#pragma unroll
        for (int mt = 0; mt < 2; ++mt) {
            int r = mt * 32 + l31;
#pragma unroll
            for (int kk = 0; kk < 4; ++kk) {
                int c8 = kk * 2 + half;
                bf16x8 kf = *reinterpret_cast<const bf16x8*>(
                    &ks[cur][r * 64 + ((c8 ^ (r & 7)) << 3)]);
                s_acc[mt] = __builtin_amdgcn_mfma_f32_32x32x16_bf16(
                    kf, qfrag[kk], s_acc[mt], 0, 0, 0);
            }
        }
        // ---- max-free softmax: p = 2^s; pack + write P (wave-private rows) ----
        float rs = 0.f;
#pragma unroll
        for (int mt = 0; mt < 2; ++mt)
#pragma unroll
            for (int g = 0; g < 4; ++g) {
                float p0 = __builtin_amdgcn_exp2f(s_acc[mt][g * 4 + 0]);
                float p1 = __builtin_amdgcn_exp2f(s_acc[mt][g * 4 + 1]);
                float p2 = __builtin_amdgcn_exp2f(s_acc[mt][g * 4 + 2]);
                float p3 = __builtin_amdgcn_exp2f(s_acc[mt][g * 4 + 3]);
                rs += (p0 + p1) + (p2 + p3);
                uint2 pk;
                pk.x = pack_bf2(p0, p1);
                pk.y = pack_bf2(p2, p3);
                // key = mt*32 + 8g + 4*half + [0..3]
                *reinterpret_cast<uint2*>(&ps[prow + mt * 32 + g * 8 + half * 4]) = pk;
            }
        l_i += rs;
        // ---- P^T B-frags: n = query (l31), k = kk*16 + half*8 + j ----
        bf16x8 pf[4];
#pragma unroll
        for (int kk = 0; kk < 4; ++kk) {
            union { uint2 u[2]; bf16x8 v; } u8;
            u8.u[0] = *reinterpret_cast<const uint2*>(&ps[prow + kk * 16 + half * 8]);
            u8.u[1] = *reinterpret_cast<const uint2*>(&ps[prow + kk * 16 + half * 8 + 4]);
            pf[kk] = u8.v;
        }
        // ---- O^T += V^T P^T : rows = d (2 nt halves), cols = 32 queries ----
#pragma unroll
        for (int nt = 0; nt < 2; ++nt) {
            int rv = nt * 32 + l31;
#pragma unroll
            for (int kk = 0; kk < 4; ++kk) {
                int c8 = kk * 2 + half;
                bf16x8 vf = *reinterpret_cast<const bf16x8*>(
                    &vs[cur][rv * 64 + ((c8 ^ (rv & 7)) << 3)]);
                o_acc[nt] = __builtin_amdgcn_mfma_f32_32x32x16_bf16(
                    vf, pf[kk], o_acc[nt], 0, 0, 0);
            }
        }
        __syncthreads();  // drains prefetch DMAs; next tile ready
    }
    // lanes l31 and l31+32 hold complementary key subsets; combine denominators
    l_i += __shfl_xor(l_i, 32, 64);
    float inv = 1.f / l_i;
    u16* orow = houtt + (size_t)(b * S + q0 + w * 32 + l31) * 512 + h * HD;
#pragma unroll
    for (int nt = 0; nt < 2; ++nt)
#pragma unroll
        for (int g = 0; g < 4; ++g) {
            uint2 pk;
            pk.x = pack_bf2(o_acc[nt][g * 4 + 0] * inv, o_acc[nt][g * 4 + 1] * inv);
            pk.y = pack_bf2(o_acc[nt][g * 4 + 2] * inv, o_acc[nt][g * 4 + 3] * inv);
            // d = nt*32 + 8g + 4*half + [0..3]
            *reinterpret_cast<uint2*>(&orow[nt * 32 + g * 8 + half * 4]) = pk;
        }
}

extern "C" void kernel_launch(void* const* d_in, const int* in_sizes, int n_in,
                              void* d_out, int out_size, void* d_ws, size_t ws_size,
                              hipStream_t stream) {
    const float* x      = (const float*)d_in[0];
    const float* gamma  = (const float*)d_in[1];
    const float* beta   = (const float*)d_in[2];
    const float* w_qkv  = (const float*)d_in[3];
    const float* b_qkv  = (const float*)d_in[4];
    const float* w_proj = (const float*)d_in[5];
    const float* b_proj = (const float*)d_in[6];
    float* out = (float*)d_out;

    char* ws = (char*)d_ws;
    float* stats = (float*)ws;                                     // 4 KB
    u16* wbf   = (u16*)(ws + 4096);                                // 2 MB (qkv+proj bf16)
    u16* xnt   = (u16*)(ws + 4096 + 2097152);                      // 8 MB [b][s][512]
    u16* qkvT  = (u16*)(ws + 4096 + 2097152 + 8388608);            // 16 MB [b][s][1024]
    u16* qkvV  = (u16*)(ws + 4096 + 2097152 + 8388608 + 16777216); // 8 MB [b][512][S]
    u16* houtt = xnt;  // alias: xnt dead after qkv GEMM

    prep<<<1280, 256, 0, stream>>>(x, w_qkv, w_proj, stats, wbf);
    gn_apply_t<<<dim3(16, 8, Bn), 256, 0, stream>>>(x, gamma, beta, stats, xnt);
    mfma_gemm<0><<<dim3(8, 12, Bn), 256, 0, stream>>>(
        wbf, xnt, b_qkv, nullptr, qkvT, qkvV, nullptr);
    attn_mfma<<<dim3(Bn * NH, S / 128), 256, 0, stream>>>(qkvT, qkvV, houtt);
    mfma_gemm<1><<<dim3(8, 4, Bn), 256, 0, stream>>>(
        wbf + 1536 * 512, houtt, b_proj, x, nullptr, nullptr, out);
}